// Round 5
// baseline (652.824 us; speedup 1.0000x reference)
//
#include <hip/hip_runtime.h>
#include <hip/hip_bf16.h>
#include <cstdint>

#define B_ 8
#define S_ 4096
#define DM 1024
#define H_ 16
#define DN 64      // head dim
#define CH 64      // chunk length
#define NC 64      // chunks per sequence
#define M_ (B_ * S_)

typedef unsigned short u16;
typedef u16 u16x8 __attribute__((ext_vector_type(8)));
typedef u16 u16x4 __attribute__((ext_vector_type(4)));
typedef float f32x4 __attribute__((ext_vector_type(4)));
typedef __bf16 bf16x8 __attribute__((ext_vector_type(8)));

__device__ __forceinline__ float bf2f(u16 u) { return __uint_as_float(((unsigned)u) << 16); }
__device__ __forceinline__ u16 f2bf(float f) { __bf16 h = (__bf16)f; return __builtin_bit_cast(u16, h); }

#define GLOAD16(gp, lp) \
  __builtin_amdgcn_global_load_lds((__attribute__((address_space(1))) const void*)(gp), \
                                   (__attribute__((address_space(3))) void*)(lp), 16, 0, 0)

// ===================== bf16 MFMA GEMM: C[m][n] = sum_k A[m][k]*B[n][k] =====================
// 128x128 tile, BK=64, 4 waves. 1-D grid of 2048 blocks with XCD-aware swizzle:
// XCD k (hw round-robin = orig%8) owns m-tiles [k*32, k*32+32), n-tiles cycling fast
// -> each A-panel fetched by exactly ONE XCD, B fully L2-resident (2 MB).
template<int MODE>  // 0: fp32 out, 1: bf16 out
__global__ __launch_bounds__(256, 4) void bgemm(
    const u16* __restrict__ A, const u16* __restrict__ Bw,
    void* __restrict__ Cout, int K)
{
  __shared__ u16 ldsA[8 * 128 * 8];
  __shared__ u16 ldsB[8 * 128 * 8];
  const int orig = blockIdx.x;
  const int swz  = (orig & 7) * 256 + (orig >> 3);   // bijective: 2048 % 8 == 0
  const int m0 = (swz >> 3) * 128;
  const int n0 = (swz & 7) * 128;
  const int t  = threadIdx.x;
  const int l  = t & 63;
  const int wid = t >> 6;
  const int wr = wid >> 1, wc = wid & 1;
  const int lr = l & 15, lk = l >> 4;

  f32x4 acc[4][4];
#pragma unroll
  for (int i = 0; i < 4; ++i)
#pragma unroll
    for (int j = 0; j < 4; ++j) acc[i][j] = (f32x4){0.f, 0.f, 0.f, 0.f};

  int cm[4], ck[4];
#pragma unroll
  for (int j = 0; j < 4; ++j) { int c = j * 256 + t; ck[j] = c >> 7; cm[j] = c & 127; }

  const int nkt = K >> 6;
  for (int kt = 0; kt < nkt; ++kt) {
#pragma unroll
    for (int j = 0; j < 4; ++j) {
      const u16* ga = A + (size_t)(m0 + cm[j]) * K + kt * 64 + ck[j] * 8;
      GLOAD16(ga, &ldsA[(j * 256 + t) * 8]);
    }
#pragma unroll
    for (int j = 0; j < 4; ++j) {
      const u16* gb = Bw + (size_t)(n0 + cm[j]) * K + kt * 64 + ck[j] * 8;
      GLOAD16(gb, &ldsB[(j * 256 + t) * 8]);
    }
    __syncthreads();
#pragma unroll
    for (int ks = 0; ks < 2; ++ks) {
      bf16x8 af[4], bfr[4];
#pragma unroll
      for (int mf = 0; mf < 4; ++mf) {
        int cell = (ks * 4 + lk) * 128 + wr * 64 + mf * 16 + lr;
        af[mf] = *reinterpret_cast<const bf16x8*>(&ldsA[cell * 8]);
      }
#pragma unroll
      for (int nf = 0; nf < 4; ++nf) {
        int cell = (ks * 4 + lk) * 128 + wc * 64 + nf * 16 + lr;
        bfr[nf] = *reinterpret_cast<const bf16x8*>(&ldsB[cell * 8]);
      }
#pragma unroll
      for (int mf = 0; mf < 4; ++mf)
#pragma unroll
        for (int nf = 0; nf < 4; ++nf)
          acc[mf][nf] = __builtin_amdgcn_mfma_f32_16x16x32_bf16(af[mf], bfr[nf], acc[mf][nf], 0, 0, 0);
    }
    __syncthreads();
  }
#pragma unroll
  for (int mf = 0; mf < 4; ++mf) {
#pragma unroll
    for (int nf = 0; nf < 4; ++nf) {
      int n = n0 + wc * 64 + nf * 16 + lr;
      int mbase = m0 + wr * 64 + mf * 16 + lk * 4;
#pragma unroll
      for (int r = 0; r < 4; ++r) {
        if (MODE == 0) ((float*)Cout)[(size_t)(mbase + r) * 1024 + n] = acc[mf][nf][r];
        else           ((u16*)Cout)[(size_t)(mbase + r) * 1024 + n] = f2bf(acc[mf][nf][r]);
      }
    }
  }
}

// ===================== fp32 -> bf16 convert (weights only) =====================
__global__ __launch_bounds__(256) void cvt32to16(const float* __restrict__ in, u16* __restrict__ out)
{
  size_t i = ((size_t)blockIdx.x * 256 + threadIdx.x) * 8;
  f32x4 a = *reinterpret_cast<const f32x4*>(&in[i]);
  f32x4 b = *reinterpret_cast<const f32x4*>(&in[i + 4]);
  u16x8 o;
#pragma unroll
  for (int j = 0; j < 4; ++j) { o[j] = f2bf(a[j]); o[4 + j] = f2bf(b[j]); }
  *reinterpret_cast<u16x8*>(&out[i]) = o;
}

// ===================== fp32 GEMM for the 16 w columns + fused x->bf16 =====================
// 2048 blocks x 16 rows (8 blocks/CU). Thread (h=t&15, r=t>>4) computes the FULL fp32
// dot wbufT[h][m0+r] (numerics identical to prior rounds). Then the block converts its
// 16 cache-hot x rows to bf16 with flat fully-coalesced u16x8 stores.
__global__ __launch_bounds__(256) void wgemm(
    const float* __restrict__ x, const float* __restrict__ ipw,
    float* __restrict__ wbufT, u16* __restrict__ xbf)
{
  const int m0 = blockIdx.x * 16;
  const int t = threadIdx.x;
  const int h = t & 15;
  const int r = t >> 4;
  const f32x4* wp = reinterpret_cast<const f32x4*>(ipw + (size_t)(1024 + h) * 1024);
  const f32x4* xp = reinterpret_cast<const f32x4*>(x + (size_t)(m0 + r) * 1024);
  f32x4 acc = (f32x4){0.f, 0.f, 0.f, 0.f};
  for (int k4 = 0; k4 < 256; ++k4) {
    f32x4 xv = xp[k4];
    f32x4 wv = wp[k4];
    acc.x = fmaf(xv.x, wv.x, acc.x);
    acc.y = fmaf(xv.y, wv.y, acc.y);
    acc.z = fmaf(xv.z, wv.z, acc.z);
    acc.w = fmaf(xv.w, wv.w, acc.w);
  }
  wbufT[(size_t)h * M_ + m0 + r] = (acc.x + acc.y) + (acc.z + acc.w);
  // fused conversion: 16 rows x 1024 cols = 16384 elems; thread t: elem = q*2048 + t*8
  const size_t base = (size_t)m0 * 1024;
#pragma unroll
  for (int q = 0; q < 8; ++q) {
    int e = q * 2048 + t * 8;
    f32x4 a = *reinterpret_cast<const f32x4*>(&x[base + e]);
    f32x4 b = *reinterpret_cast<const f32x4*>(&x[base + e + 4]);
    u16x8 o;
#pragma unroll
    for (int j = 0; j < 4; ++j) { o[j] = f2bf(a[j]); o[4 + j] = f2bf(b[j]); }
    *reinterpret_cast<u16x8*>(&xbf[base + e]) = o;
  }
}

// ===================== fused per-(b,h,c): conv + cumsum + L(MFMA) + Y_diag + norm + states =====================
__global__ __launch_bounds__(256) void chunk_kernel(
    const u16* __restrict__ xi,        // [M][1024] bf16 (in_proj out, pre-conv)
    const float* __restrict__ cw, const float* __restrict__ cb,
    const float* __restrict__ wbufT, const float* __restrict__ w_base,
    u16* __restrict__ ybuf, float* __restrict__ Acum, float* __restrict__ acbuf,
    float* __restrict__ normd, float* __restrict__ states, float* __restrict__ ndbuf)
{
  int bi = blockIdx.x;               // b*1024 + h*64 + c
  int c  = bi & 63;
  int h  = (bi >> 6) & 15;
  int b  = bi >> 10;
  int bh = b * 16 + h;
  int t  = threadIdx.x;
  __shared__ u16 xis[67][64];        // raw xi tile (halo 3), bf16
  __shared__ u16 xsT[64][66];        // conv output, transposed [n][s], bf16
  __shared__ float pc[CH], m1s[CH], dsv[CH];
  __shared__ float wls[4][64];       // conv weights transposed [tap][ch]
  __shared__ float cbs[64];
  size_t m0 = (size_t)b * S_ + (size_t)c * CH;
  size_t abase = ((size_t)bh * NC + c) * CH;

  wls[t & 3][t >> 2] = cw[(size_t)h * 256 + t];
  if (t < 64) cbs[t] = cb[h * 64 + t];

  {
    int g8  = t & 7;
    int hr0 = t >> 3;
    for (int hr = hr0; hr < 67; hr += 32) {
      u16x8 v = {0, 0, 0, 0, 0, 0, 0, 0};
      if (!(c == 0 && hr < 3))
        v = *reinterpret_cast<const u16x8*>(&xi[(m0 - 3 + hr) * DM + h * 64 + g8 * 8]);
      *reinterpret_cast<u16x8*>(&xis[hr][g8 * 8]) = v;
    }
  }

  if (t < 64) {
    float p = wbufT[(size_t)h * M_ + m0 + t] * w_base[h];
#pragma unroll
    for (int off = 1; off < 64; off <<= 1) {
      float v = __shfl_up(p, off);
      if (t >= off) p += v;
    }
    Acum[abase + t] = p;
    if (t == 63) acbuf[(size_t)bh * NC + c] = p;
    pc[t] = p;
    float rmin = p;
#pragma unroll
    for (int off = 1; off < 64; off <<= 1) {
      float v = __shfl_up(rmin, off);
      if (t >= off) rmin = fminf(rmin, v);
    }
    m1s[t] = p - rmin;
    float minall = __shfl(rmin, 63);
    dsv[t] = __expf(minall - p);
  }
  __syncthreads();

  // conv: thread owns channel n, 16 consecutive rows; sliding 4-tap window
  {
    int n  = t & 63;
    int lb = (t >> 6) * 16;
    float w0 = wls[0][n], w1 = wls[1][n], w2 = wls[2][n], w3 = wls[3][n];
    float bias = cbs[n];
    float a = bf2f(xis[lb + 0][n]);
    float bv = bf2f(xis[lb + 1][n]);
    float cv = bf2f(xis[lb + 2][n]);
    u16x8 o0, o1;
#pragma unroll
    for (int r = 0; r < 16; ++r) {
      float dv = bf2f(xis[lb + r + 3][n]);
      float s = fmaf(w3, dv, fmaf(w2, cv, fmaf(w1, bv, fmaf(w0, a, bias))));
      if (r < 8) o0[r] = f2bf(s); else o1[r - 8] = f2bf(s);
      a = bv; bv = cv; cv = dv;
    }
    *reinterpret_cast<u16x8*>(&xsT[n][lb]) = o0;
    *reinterpret_cast<u16x8*>(&xsT[n][lb + 8]) = o1;
  }
  __syncthreads();

  // MFMA phase: wave w owns output rows w*16..w*16+15.
  {
    int w = t >> 6, l = t & 63;
    int lr = l & 15, lk = l >> 4;
    int row = w * 16 + lr;
    float pr = pc[row], m1r = m1s[row];
    bf16x8 afr[2];
    float np = 0.f;
#pragma unroll
    for (int ks = 0; ks < 2; ++ks) {
      int sbase = ks * 32 + lk * 8;
      u16x8 av;
#pragma unroll
      for (int j = 0; j < 8; ++j) {
        int s = sbase + j;
        float L = (s <= row) ? __expf(pr - pc[s] - m1r) : 0.f;
        np += L;
        av[j] = f2bf(L);
      }
      afr[ks] = __builtin_bit_cast(bf16x8, av);
    }
    np += __shfl_xor(np, 16);
    np += __shfl_xor(np, 32);
    if (lk == 0) normd[abase + row] = np;

    f32x4 acc[4];
#pragma unroll
    for (int nf = 0; nf < 4; ++nf) acc[nf] = (f32x4){0.f, 0.f, 0.f, 0.f};
#pragma unroll
    for (int ks = 0; ks < 2; ++ks)
#pragma unroll
      for (int nf = 0; nf < 4; ++nf) {
        bf16x8 bfr = *reinterpret_cast<const bf16x8*>(&xsT[nf * 16 + lr][ks * 32 + lk * 8]);
        acc[nf] = __builtin_amdgcn_mfma_f32_16x16x32_bf16(afr[ks], bfr, acc[nf], 0, 0, 0);
      }
#pragma unroll
    for (int nf = 0; nf < 4; ++nf)
#pragma unroll
      for (int r = 0; r < 4; ++r)
        ybuf[(m0 + w * 16 + lk * 4 + r) * DM + h * 64 + nf * 16 + lr] = f2bf(acc[nf][r]);
  }

  if (t < 64) {
    float acc = 0.f;
#pragma unroll
    for (int l8 = 0; l8 < 64; l8 += 8) {
      u16x8 xv = *reinterpret_cast<const u16x8*>(&xsT[t][l8]);
#pragma unroll
      for (int j = 0; j < 8; ++j) acc = fmaf(dsv[l8 + j], bf2f(xv[j]), acc);
    }
    states[((size_t)bh * NC + c) * DN + t] = acc;
    float v = dsv[t];
#pragma unroll
    for (int off = 32; off >= 1; off >>= 1) v += __shfl_down(v, off);
    if (t == 0) ndbuf[(size_t)bh * NC + c] = v;
  }
}

// ===================== inter-chunk propagation =====================
__global__ __launch_bounds__(256) void interchunk_kernel(
    const float* __restrict__ acbuf, const float* __restrict__ states,
    const float* __restrict__ ndbuf, float* __restrict__ nstates, float* __restrict__ nndbuf)
{
  int bh = blockIdx.x;
  int t  = threadIdx.x;
  __shared__ float Ssum[NC], minP[NC], ndl[NC];
  if (t < 64) {
    float ac = acbuf[(size_t)bh * NC + t];
    float S = ac;
#pragma unroll
    for (int off = 1; off < 64; off <<= 1) {
      float v = __shfl_up(S, off);
      if (t >= off) S += v;
    }
    float Pc = S - ac;
    float mp = Pc;
#pragma unroll
    for (int off = 1; off < 64; off <<= 1) {
      float v = __shfl_up(mp, off);
      if (t >= off) mp = fminf(mp, v);
    }
    Ssum[t] = S;
    minP[t] = mp;
    ndl[t]  = ndbuf[(size_t)bh * NC + t];
  }
  __syncthreads();
  int n  = t & 63;
  int r0 = t >> 6;
  for (int r = 0; r < 16; ++r) {
    int z = r0 + r * 4;
    float mpz = minP[z];
    float acc = 0.f;
    for (int j = 0; j < z; ++j) {
      float e = __expf(mpz - Ssum[j]);
      acc = fmaf(e, states[((size_t)bh * NC + j) * DN + n], acc);
    }
    nstates[((size_t)bh * NC + z) * DN + n] = acc;
  }
  if (t < 64) {
    int z = t;
    float mpz = minP[z];
    float acc = 0.f;
    for (int j = 0; j < z; ++j) acc = fmaf(__expf(mpz - Ssum[j]), ndl[j], acc);
    nndbuf[(size_t)bh * NC + z] = acc;
  }
}

// ===================== final: y = (Y_diag + states_off*sdo) / (norm_diag + nd_off*sdo) =====================
__global__ __launch_bounds__(256) void final_kernel(
    const float* __restrict__ Acum, const float* __restrict__ normd,
    const float* __restrict__ nstates, const float* __restrict__ nndbuf,
    u16* __restrict__ ybuf)
{
  int bi = blockIdx.x;
  int c  = bi & 63;
  int h  = (bi >> 6) & 15;
  int b  = bi >> 10;
  int bh = b * 16 + h;
  int t  = threadIdx.x;
  __shared__ float sdo[CH], nrm[CH], sto[DN];
  __shared__ float ndo_s;
  size_t abase = ((size_t)bh * NC + c) * CH;
  if (t < 64) {
    float p = Acum[abase + t];
    float m3 = p;
#pragma unroll
    for (int off = 32; off >= 1; off >>= 1) m3 = fmaxf(m3, __shfl_down(m3, off));
    m3 = __shfl(m3, 0);
    sdo[t] = __expf(p - m3);
    nrm[t] = normd[abase + t];
    sto[t] = nstates[((size_t)bh * NC + c) * DN + t];
    if (t == 0) ndo_s = nndbuf[(size_t)bh * NC + c];
  }
  __syncthreads();
  size_t m0 = (size_t)b * S_ + (size_t)c * CH;
  int g  = t & 7;
  int l0 = t >> 3;
  float ndo = ndo_s;
  for (int li = l0; li < 64; li += 32) {
    size_t a = (m0 + li) * DM + h * DN + g * 8;
    u16x8 v = *reinterpret_cast<u16x8*>(&ybuf[a]);
    float sd = sdo[li];
    float rec = 1.f / (nrm[li] + ndo * sd);
    u16x8 o;
#pragma unroll
    for (int jj = 0; jj < 8; ++jj) {
      float yd = bf2f(v[jj]);
      o[jj] = f2bf((yd + sto[g * 8 + jj] * sd) * rec);
    }
    *reinterpret_cast<u16x8*>(&ybuf[a]) = o;
  }
}

// ===================== launch =====================
extern "C" void kernel_launch(void* const* d_in, const int* in_sizes, int n_in,
                              void* d_out, int out_size, void* d_ws, size_t ws_size,
                              hipStream_t stream) {
  const float* x          = (const float*)d_in[0];
  const float* in_proj_w  = (const float*)d_in[1];
  const float* conv_w     = (const float*)d_in[2];
  const float* conv_b     = (const float*)d_in[3];
  const float* w_base     = (const float*)d_in[4];
  const float* out_proj_w = (const float*)d_in[5];
  float* out = (float*)d_out;
  char* ws = (char*)d_ws;

  // workspace layout (~146 MB)
  u16*   wbf_in  = (u16*)  (ws + 0);
  u16*   wbf_out = (u16*)  (ws + 2097152);
  float* wbufT   = (float*)(ws + 4194304);
  float* Acum    = (float*)(ws + 6291456);
  float* acbuf   = (float*)(ws + 8388608);
  float* normd   = (float*)(ws + 8421376);
  float* states  = (float*)(ws + 10518528);
  float* ndbuf   = (float*)(ws + 12615680);
  float* nstates = (float*)(ws + 12648448);
  float* nndbuf  = (float*)(ws + 14745600);
  u16*   xbf     = (u16*)  (ws + 14778368);   // [M][1024] bf16 of x; reused as ybuf
  u16*   xibf    = (u16*)  (ws + 81887232);   // [M][1024] bf16 xi (in_proj out)
  u16*   ybuf    = xbf;

  wgemm<<<2048, 256, 0, stream>>>(x, in_proj_w, wbufT, xbf);
  cvt32to16<<<512, 256, 0, stream>>>(in_proj_w, wbf_in);
  cvt32to16<<<512, 256, 0, stream>>>(out_proj_w, wbf_out);
  bgemm<1><<<2048, 256, 0, stream>>>(xbf, wbf_in, (void*)xibf, DM);
  chunk_kernel<<<8192, 256, 0, stream>>>(xibf, conv_w, conv_b, wbufT, w_base,
                                         ybuf, Acum, acbuf, normd, states, ndbuf);
  interchunk_kernel<<<128, 256, 0, stream>>>(acbuf, states, ndbuf, nstates, nndbuf);
  final_kernel<<<8192, 256, 0, stream>>>(Acum, normd, nstates, nndbuf, ybuf);
  bgemm<0><<<2048, 256, 0, stream>>>(ybuf, wbf_out, (void*)out, DM);
}

// Round 6
// 415.965 us; speedup vs baseline: 1.5694x; 1.5694x over previous
//
#include <hip/hip_runtime.h>
#include <hip/hip_bf16.h>
#include <cstdint>

#define B_ 8
#define S_ 4096
#define DM 1024
#define H_ 16
#define DN 64      // head dim
#define CH 64      // chunk length
#define NC 64      // chunks per sequence
#define M_ (B_ * S_)

typedef unsigned short u16;
typedef u16 u16x8 __attribute__((ext_vector_type(8)));
typedef u16 u16x4 __attribute__((ext_vector_type(4)));
typedef float f32x4 __attribute__((ext_vector_type(4)));
typedef __bf16 bf16x8 __attribute__((ext_vector_type(8)));

__device__ __forceinline__ float bf2f(u16 u) { return __uint_as_float(((unsigned)u) << 16); }
__device__ __forceinline__ u16 f2bf(float f) { __bf16 h = (__bf16)f; return __builtin_bit_cast(u16, h); }

#define GLOAD16(gp, lp) \
  __builtin_amdgcn_global_load_lds((__attribute__((address_space(1))) const void*)(gp), \
                                   (__attribute__((address_space(3))) void*)(lp), 16, 0, 0)

// ===================== bf16 MFMA GEMM: C[m][n] = sum_k A[m][k]*B[n][k] =====================
// 128x128 tile, BK=64, 4 waves. XCD-aware swizzle: each XCD owns a contiguous m-range.
template<int MODE>  // 0: fp32 out, 1: bf16 out
__global__ __launch_bounds__(256, 4) void bgemm(
    const u16* __restrict__ A, const u16* __restrict__ Bw,
    void* __restrict__ Cout, int K)
{
  __shared__ u16 ldsA[8 * 128 * 8];
  __shared__ u16 ldsB[8 * 128 * 8];
  const int orig = blockIdx.x;
  const int swz  = (orig & 7) * 256 + (orig >> 3);   // bijective: 2048 % 8 == 0
  const int m0 = (swz >> 3) * 128;
  const int n0 = (swz & 7) * 128;
  const int t  = threadIdx.x;
  const int l  = t & 63;
  const int wid = t >> 6;
  const int wr = wid >> 1, wc = wid & 1;
  const int lr = l & 15, lk = l >> 4;

  f32x4 acc[4][4];
#pragma unroll
  for (int i = 0; i < 4; ++i)
#pragma unroll
    for (int j = 0; j < 4; ++j) acc[i][j] = (f32x4){0.f, 0.f, 0.f, 0.f};

  int cm[4], ck[4];
#pragma unroll
  for (int j = 0; j < 4; ++j) { int c = j * 256 + t; ck[j] = c >> 7; cm[j] = c & 127; }

  const int nkt = K >> 6;
  for (int kt = 0; kt < nkt; ++kt) {
#pragma unroll
    for (int j = 0; j < 4; ++j) {
      const u16* ga = A + (size_t)(m0 + cm[j]) * K + kt * 64 + ck[j] * 8;
      GLOAD16(ga, &ldsA[(j * 256 + t) * 8]);
    }
#pragma unroll
    for (int j = 0; j < 4; ++j) {
      const u16* gb = Bw + (size_t)(n0 + cm[j]) * K + kt * 64 + ck[j] * 8;
      GLOAD16(gb, &ldsB[(j * 256 + t) * 8]);
    }
    __syncthreads();
#pragma unroll
    for (int ks = 0; ks < 2; ++ks) {
      bf16x8 af[4], bfr[4];
#pragma unroll
      for (int mf = 0; mf < 4; ++mf) {
        int cell = (ks * 4 + lk) * 128 + wr * 64 + mf * 16 + lr;
        af[mf] = *reinterpret_cast<const bf16x8*>(&ldsA[cell * 8]);
      }
#pragma unroll
      for (int nf = 0; nf < 4; ++nf) {
        int cell = (ks * 4 + lk) * 128 + wc * 64 + nf * 16 + lr;
        bfr[nf] = *reinterpret_cast<const bf16x8*>(&ldsB[cell * 8]);
      }
#pragma unroll
      for (int mf = 0; mf < 4; ++mf)
#pragma unroll
        for (int nf = 0; nf < 4; ++nf)
          acc[mf][nf] = __builtin_amdgcn_mfma_f32_16x16x32_bf16(af[mf], bfr[nf], acc[mf][nf], 0, 0, 0);
    }
    __syncthreads();
  }
#pragma unroll
  for (int mf = 0; mf < 4; ++mf) {
#pragma unroll
    for (int nf = 0; nf < 4; ++nf) {
      int n = n0 + wc * 64 + nf * 16 + lr;
      int mbase = m0 + wr * 64 + mf * 16 + lk * 4;
#pragma unroll
      for (int r = 0; r < 4; ++r) {
        if (MODE == 0) ((float*)Cout)[(size_t)(mbase + r) * 1024 + n] = acc[mf][nf][r];
        else           ((u16*)Cout)[(size_t)(mbase + r) * 1024 + n] = f2bf(acc[mf][nf][r]);
      }
    }
  }
}

// ===================== fp32 -> bf16 convert (weights) =====================
__global__ __launch_bounds__(256) void cvt32to16(const float* __restrict__ in, u16* __restrict__ out)
{
  size_t i = ((size_t)blockIdx.x * 256 + threadIdx.x) * 8;
  f32x4 a = *reinterpret_cast<const f32x4*>(&in[i]);
  f32x4 b = *reinterpret_cast<const f32x4*>(&in[i + 4]);
  u16x8 o;
#pragma unroll
  for (int j = 0; j < 4; ++j) { o[j] = f2bf(a[j]); o[4 + j] = f2bf(b[j]); }
  *reinterpret_cast<u16x8*>(&out[i]) = o;
}

// ===================== residual (lo) of bf16 rounding for the 16 w rows =====================
__global__ __launch_bounds__(256) void cvtlo(const float* __restrict__ ipw, u16* __restrict__ wlo)
{
  size_t e = ((size_t)blockIdx.x * 256 + threadIdx.x) * 8;   // 16384 elems total
  f32x4 a = *reinterpret_cast<const f32x4*>(&ipw[1048576 + e]);
  f32x4 b = *reinterpret_cast<const f32x4*>(&ipw[1048576 + e + 4]);
  u16x8 o;
#pragma unroll
  for (int j = 0; j < 4; ++j) {
    u16 h = f2bf(a[j]); o[j]     = f2bf(a[j] - bf2f(h));
    u16 g = f2bf(b[j]); o[4 + j] = f2bf(b[j] - bf2f(g));
  }
  *reinterpret_cast<u16x8*>(&wlo[e]) = o;
}

// ===================== wsplit: x->bf16 (hi) + compensated-MFMA w projection =====================
// Block = 64 rows, 256 threads (4 waves). Streams x fp32 coalesced; per 64-col K-tile:
// registers hold hi=bf16(x), lo=bf16(x-hi); hi goes to xbf (global) and LDS; lo to LDS.
// wbufT[h][m] = x @ ipw[1024+h]^T via 3 MFMAs/ks: hi*wh + lo*wh + hi*wl  (error ~2^-18).
// LDS layout [row][kg^(row&7)][8] u16 — linear writes, 2-way-conflict reads (free).
__global__ __launch_bounds__(256) void wsplit(
    const float* __restrict__ x, const u16* __restrict__ wbf, const u16* __restrict__ wlo,
    u16* __restrict__ xbf, float* __restrict__ wbufT)
{
  __shared__ u16 hi[64 * 64];   // 8 KB
  __shared__ u16 lo[64 * 64];   // 8 KB
  const int r0 = blockIdx.x * 64;
  const int t  = threadIdx.x;
  const int w  = t >> 6, l = t & 63;
  const int lr = l & 15, lk = l >> 4;
  const int c8   = t & 7;       // staging col-chunk (8 floats)
  const int srow = t >> 3;      // staging row 0..31 (+32 on pass 2)

  f32x4 acc = (f32x4){0.f, 0.f, 0.f, 0.f};

  for (int kt = 0; kt < 16; ++kt) {
    __syncthreads();            // previous iter's LDS reads done
#pragma unroll
    for (int p = 0; p < 2; ++p) {
      int row = srow + 32 * p;
      const float* gp = &x[(size_t)(r0 + row) * 1024 + kt * 64 + c8 * 8];
      f32x4 a = *reinterpret_cast<const f32x4*>(gp);
      f32x4 b = *reinterpret_cast<const f32x4*>(gp + 4);
      u16x8 h8, l8;
#pragma unroll
      for (int j = 0; j < 4; ++j) {
        u16 ha = f2bf(a[j]); h8[j]     = ha; l8[j]     = f2bf(a[j] - bf2f(ha));
        u16 hb = f2bf(b[j]); h8[4 + j] = hb; l8[4 + j] = f2bf(b[j] - bf2f(hb));
      }
      int cell = row * 8 + (c8 ^ (row & 7));
      *reinterpret_cast<u16x8*>(&hi[cell * 8]) = h8;
      *reinterpret_cast<u16x8*>(&lo[cell * 8]) = l8;
      *reinterpret_cast<u16x8*>(&xbf[(size_t)(r0 + row) * 1024 + kt * 64 + c8 * 8]) = h8;
    }
    __syncthreads();
    // MFMA: wave w owns x rows w*16..w*16+15; C cols = 16 heads.
#pragma unroll
    for (int ks = 0; ks < 2; ++ks) {
      int row  = w * 16 + lr;
      int cell = row * 8 + ((ks * 4 + lk) ^ (row & 7));
      bf16x8 ah = *reinterpret_cast<const bf16x8*>(&hi[cell * 8]);
      bf16x8 al = *reinterpret_cast<const bf16x8*>(&lo[cell * 8]);
      bf16x8 bh = *reinterpret_cast<const bf16x8*>(&wbf[(size_t)(1024 + lr) * 1024 + kt * 64 + ks * 32 + lk * 8]);
      bf16x8 bl = *reinterpret_cast<const bf16x8*>(&wlo[(size_t)lr * 1024 + kt * 64 + ks * 32 + lk * 8]);
      acc = __builtin_amdgcn_mfma_f32_16x16x32_bf16(ah, bh, acc, 0, 0, 0);
      acc = __builtin_amdgcn_mfma_f32_16x16x32_bf16(al, bh, acc, 0, 0, 0);
      acc = __builtin_amdgcn_mfma_f32_16x16x32_bf16(ah, bl, acc, 0, 0, 0);
    }
  }
  // C mapping: col=lane&15 (=h), row=(lane>>4)*4+reg
#pragma unroll
  for (int r = 0; r < 4; ++r)
    wbufT[(size_t)lr * M_ + r0 + w * 16 + lk * 4 + r] = acc[r];
}

// ===================== fused per-(b,h,c): conv + cumsum + L(MFMA) + Y_diag + norm + states =====================
__global__ __launch_bounds__(256) void chunk_kernel(
    const u16* __restrict__ xi,        // [M][1024] bf16 (in_proj out, pre-conv)
    const float* __restrict__ cw, const float* __restrict__ cb,
    const float* __restrict__ wbufT, const float* __restrict__ w_base,
    u16* __restrict__ ybuf, float* __restrict__ Acum, float* __restrict__ acbuf,
    float* __restrict__ normd, float* __restrict__ states, float* __restrict__ ndbuf)
{
  int bi = blockIdx.x;               // b*1024 + h*64 + c
  int c  = bi & 63;
  int h  = (bi >> 6) & 15;
  int b  = bi >> 10;
  int bh = b * 16 + h;
  int t  = threadIdx.x;
  __shared__ u16 xis[67][64];        // raw xi tile (halo 3), bf16
  __shared__ u16 xsT[64][66];        // conv output, transposed [n][s], bf16
  __shared__ float pc[CH], m1s[CH], dsv[CH];
  __shared__ float wls[4][64];       // conv weights transposed [tap][ch]
  __shared__ float cbs[64];
  size_t m0 = (size_t)b * S_ + (size_t)c * CH;
  size_t abase = ((size_t)bh * NC + c) * CH;

  wls[t & 3][t >> 2] = cw[(size_t)h * 256 + t];
  if (t < 64) cbs[t] = cb[h * 64 + t];

  {
    int g8  = t & 7;
    int hr0 = t >> 3;
    for (int hr = hr0; hr < 67; hr += 32) {
      u16x8 v = {0, 0, 0, 0, 0, 0, 0, 0};
      if (!(c == 0 && hr < 3))
        v = *reinterpret_cast<const u16x8*>(&xi[(m0 - 3 + hr) * DM + h * 64 + g8 * 8]);
      *reinterpret_cast<u16x8*>(&xis[hr][g8 * 8]) = v;
    }
  }

  if (t < 64) {
    float p = wbufT[(size_t)h * M_ + m0 + t] * w_base[h];
#pragma unroll
    for (int off = 1; off < 64; off <<= 1) {
      float v = __shfl_up(p, off);
      if (t >= off) p += v;
    }
    Acum[abase + t] = p;
    if (t == 63) acbuf[(size_t)bh * NC + c] = p;
    pc[t] = p;
    float rmin = p;
#pragma unroll
    for (int off = 1; off < 64; off <<= 1) {
      float v = __shfl_up(rmin, off);
      if (t >= off) rmin = fminf(rmin, v);
    }
    m1s[t] = p - rmin;
    float minall = __shfl(rmin, 63);
    dsv[t] = __expf(minall - p);
  }
  __syncthreads();

  // conv: thread owns channel n, 16 consecutive rows; sliding 4-tap window
  {
    int n  = t & 63;
    int lb = (t >> 6) * 16;
    float w0 = wls[0][n], w1 = wls[1][n], w2 = wls[2][n], w3 = wls[3][n];
    float bias = cbs[n];
    float a = bf2f(xis[lb + 0][n]);
    float bv = bf2f(xis[lb + 1][n]);
    float cv = bf2f(xis[lb + 2][n]);
    u16x8 o0, o1;
#pragma unroll
    for (int r = 0; r < 16; ++r) {
      float dv = bf2f(xis[lb + r + 3][n]);
      float s = fmaf(w3, dv, fmaf(w2, cv, fmaf(w1, bv, fmaf(w0, a, bias))));
      if (r < 8) o0[r] = f2bf(s); else o1[r - 8] = f2bf(s);
      a = bv; bv = cv; cv = dv;
    }
    *reinterpret_cast<u16x8*>(&xsT[n][lb]) = o0;
    *reinterpret_cast<u16x8*>(&xsT[n][lb + 8]) = o1;
  }
  __syncthreads();

  // MFMA phase: wave w owns output rows w*16..w*16+15.
  {
    int w = t >> 6, l = t & 63;
    int lr = l & 15, lk = l >> 4;
    int row = w * 16 + lr;
    float pr = pc[row], m1r = m1s[row];
    bf16x8 afr[2];
    float np = 0.f;
#pragma unroll
    for (int ks = 0; ks < 2; ++ks) {
      int sbase = ks * 32 + lk * 8;
      u16x8 av;
#pragma unroll
      for (int j = 0; j < 8; ++j) {
        int s = sbase + j;
        float L = (s <= row) ? __expf(pr - pc[s] - m1r) : 0.f;
        np += L;
        av[j] = f2bf(L);
      }
      afr[ks] = __builtin_bit_cast(bf16x8, av);
    }
    np += __shfl_xor(np, 16);
    np += __shfl_xor(np, 32);
    if (lk == 0) normd[abase + row] = np;

    f32x4 acc[4];
#pragma unroll
    for (int nf = 0; nf < 4; ++nf) acc[nf] = (f32x4){0.f, 0.f, 0.f, 0.f};
#pragma unroll
    for (int ks = 0; ks < 2; ++ks)
#pragma unroll
      for (int nf = 0; nf < 4; ++nf) {
        bf16x8 bfr = *reinterpret_cast<const bf16x8*>(&xsT[nf * 16 + lr][ks * 32 + lk * 8]);
        acc[nf] = __builtin_amdgcn_mfma_f32_16x16x32_bf16(afr[ks], bfr, acc[nf], 0, 0, 0);
      }
#pragma unroll
    for (int nf = 0; nf < 4; ++nf)
#pragma unroll
      for (int r = 0; r < 4; ++r)
        ybuf[(m0 + w * 16 + lk * 4 + r) * DM + h * 64 + nf * 16 + lr] = f2bf(acc[nf][r]);
  }

  if (t < 64) {
    float acc = 0.f;
#pragma unroll
    for (int l8 = 0; l8 < 64; l8 += 8) {
      u16x8 xv = *reinterpret_cast<const u16x8*>(&xsT[t][l8]);
#pragma unroll
      for (int j = 0; j < 8; ++j) acc = fmaf(dsv[l8 + j], bf2f(xv[j]), acc);
    }
    states[((size_t)bh * NC + c) * DN + t] = acc;
    float v = dsv[t];
#pragma unroll
    for (int off = 32; off >= 1; off >>= 1) v += __shfl_down(v, off);
    if (t == 0) ndbuf[(size_t)bh * NC + c] = v;
  }
}

// ===================== inter-chunk propagation =====================
__global__ __launch_bounds__(256) void interchunk_kernel(
    const float* __restrict__ acbuf, const float* __restrict__ states,
    const float* __restrict__ ndbuf, float* __restrict__ nstates, float* __restrict__ nndbuf)
{
  int bh = blockIdx.x;
  int t  = threadIdx.x;
  __shared__ float Ssum[NC], minP[NC], ndl[NC];
  if (t < 64) {
    float ac = acbuf[(size_t)bh * NC + t];
    float S = ac;
#pragma unroll
    for (int off = 1; off < 64; off <<= 1) {
      float v = __shfl_up(S, off);
      if (t >= off) S += v;
    }
    float Pc = S - ac;
    float mp = Pc;
#pragma unroll
    for (int off = 1; off < 64; off <<= 1) {
      float v = __shfl_up(mp, off);
      if (t >= off) mp = fminf(mp, v);
    }
    Ssum[t] = S;
    minP[t] = mp;
    ndl[t]  = ndbuf[(size_t)bh * NC + t];
  }
  __syncthreads();
  int n  = t & 63;
  int r0 = t >> 6;
  for (int r = 0; r < 16; ++r) {
    int z = r0 + r * 4;
    float mpz = minP[z];
    float acc = 0.f;
    for (int j = 0; j < z; ++j) {
      float e = __expf(mpz - Ssum[j]);
      acc = fmaf(e, states[((size_t)bh * NC + j) * DN + n], acc);
    }
    nstates[((size_t)bh * NC + z) * DN + n] = acc;
  }
  if (t < 64) {
    int z = t;
    float mpz = minP[z];
    float acc = 0.f;
    for (int j = 0; j < z; ++j) acc = fmaf(__expf(mpz - Ssum[j]), ndl[j], acc);
    nndbuf[(size_t)bh * NC + z] = acc;
  }
}

// ===================== final: y = (Y_diag + states_off*sdo) / (norm_diag + nd_off*sdo) =====================
__global__ __launch_bounds__(256) void final_kernel(
    const float* __restrict__ Acum, const float* __restrict__ normd,
    const float* __restrict__ nstates, const float* __restrict__ nndbuf,
    u16* __restrict__ ybuf)
{
  int bi = blockIdx.x;
  int c  = bi & 63;
  int h  = (bi >> 6) & 15;
  int b  = bi >> 10;
  int bh = b * 16 + h;
  int t  = threadIdx.x;
  __shared__ float sdo[CH], nrm[CH], sto[DN];
  __shared__ float ndo_s;
  size_t abase = ((size_t)bh * NC + c) * CH;
  if (t < 64) {
    float p = Acum[abase + t];
    float m3 = p;
#pragma unroll
    for (int off = 32; off >= 1; off >>= 1) m3 = fmaxf(m3, __shfl_down(m3, off));
    m3 = __shfl(m3, 0);
    sdo[t] = __expf(p - m3);
    nrm[t] = normd[abase + t];
    sto[t] = nstates[((size_t)bh * NC + c) * DN + t];
    if (t == 0) ndo_s = nndbuf[(size_t)bh * NC + c];
  }
  __syncthreads();
  size_t m0 = (size_t)b * S_ + (size_t)c * CH;
  int g  = t & 7;
  int l0 = t >> 3;
  float ndo = ndo_s;
  for (int li = l0; li < 64; li += 32) {
    size_t a = (m0 + li) * DM + h * DN + g * 8;
    u16x8 v = *reinterpret_cast<u16x8*>(&ybuf[a]);
    float sd = sdo[li];
    float rec = 1.f / (nrm[li] + ndo * sd);
    u16x8 o;
#pragma unroll
    for (int jj = 0; jj < 8; ++jj) {
      float yd = bf2f(v[jj]);
      o[jj] = f2bf((yd + sto[g * 8 + jj] * sd) * rec);
    }
    *reinterpret_cast<u16x8*>(&ybuf[a]) = o;
  }
}

// ===================== launch =====================
extern "C" void kernel_launch(void* const* d_in, const int* in_sizes, int n_in,
                              void* d_out, int out_size, void* d_ws, size_t ws_size,
                              hipStream_t stream) {
  const float* x          = (const float*)d_in[0];
  const float* in_proj_w  = (const float*)d_in[1];
  const float* conv_w     = (const float*)d_in[2];
  const float* conv_b     = (const float*)d_in[3];
  const float* w_base     = (const float*)d_in[4];
  const float* out_proj_w = (const float*)d_in[5];
  float* out = (float*)d_out;
  char* ws = (char*)d_ws;

  // workspace layout (~149 MB)
  u16*   wbf_in  = (u16*)  (ws + 0);          // [1040][1024] bf16 (all in_proj rows)
  u16*   wbf_out = (u16*)  (ws + 2129920);
  u16*   wlo16   = (u16*)  (ws + 4227072);    // [16][1024] bf16 residuals
  float* wbufT   = (float*)(ws + 4259840);
  float* Acum    = (float*)(ws + 6356992);
  float* acbuf   = (float*)(ws + 8454144);
  float* normd   = (float*)(ws + 8486912);
  float* states  = (float*)(ws + 10584064);
  float* ndbuf   = (float*)(ws + 12681216);
  float* nstates = (float*)(ws + 12713984);
  float* nndbuf  = (float*)(ws + 14811136);
  u16*   xbf     = (u16*)  (ws + 14843904);   // [M][1024] bf16 of x; reused as ybuf
  u16*   xibf    = (u16*)  (ws + 81952768);   // [M][1024] bf16 xi (in_proj out)
  u16*   ybuf    = xbf;

  cvt32to16<<<520, 256, 0, stream>>>(in_proj_w, wbf_in);     // 1040 rows incl. w rows
  cvt32to16<<<512, 256, 0, stream>>>(out_proj_w, wbf_out);
  cvtlo<<<8, 256, 0, stream>>>(in_proj_w, wlo16);
  wsplit<<<512, 256, 0, stream>>>(x, wbf_in, wlo16, xbf, wbufT);
  bgemm<1><<<2048, 256, 0, stream>>>(xbf, wbf_in, (void*)xibf, DM);
  chunk_kernel<<<8192, 256, 0, stream>>>(xibf, conv_w, conv_b, wbufT, w_base,
                                         ybuf, Acum, acbuf, normd, states, ndbuf);
  interchunk_kernel<<<128, 256, 0, stream>>>(acbuf, states, ndbuf, nstates, nndbuf);
  final_kernel<<<8192, 256, 0, stream>>>(Acum, normd, nstates, nndbuf, ybuf);
  bgemm<0><<<2048, 256, 0, stream>>>(ybuf, wbf_out, (void*)out, DM);
}

// Round 7
// 289.956 us; speedup vs baseline: 2.2515x; 1.4346x over previous
//
#include <hip/hip_runtime.h>
#include <hip/hip_bf16.h>
#include <cstdint>

#define B_ 8
#define S_ 4096
#define DM 1024
#define H_ 16
#define DN 64      // head dim
#define CH 64      // chunk length
#define NC 64      // chunks per sequence
#define M_ (B_ * S_)

typedef unsigned short u16;
typedef u16 u16x8 __attribute__((ext_vector_type(8)));
typedef u16 u16x4 __attribute__((ext_vector_type(4)));
typedef float f32x4 __attribute__((ext_vector_type(4)));
typedef __bf16 bf16x8 __attribute__((ext_vector_type(8)));

__device__ __forceinline__ float bf2f(u16 u) { return __uint_as_float(((unsigned)u) << 16); }
__device__ __forceinline__ u16 f2bf(float f) { __bf16 h = (__bf16)f; return __builtin_bit_cast(u16, h); }

#define GLOAD16(gp, lp) \
  __builtin_amdgcn_global_load_lds((__attribute__((address_space(1))) const void*)(gp), \
                                   (__attribute__((address_space(3))) void*)(lp), 16, 0, 0)

// ===================== bf16 MFMA GEMM: C[m][n] = sum_k A[m][k]*B[n][k] =====================
// 128x128 tile, BK=64, 4 waves. XCD-aware block swizzle (T1).
// Staging (coalesced + T2 swizzle): flat = j*256+t; row = flat>>3; ck' = flat&7.
// Each 8-lane group reads 128 B of ONE row contiguously; the global k-chunk is
// pre-swizzled (ck = ck' ^ (row&7)) so the linear global_load_lds dest yields a
// bank-conflict-free LDS layout. Fragment reads use cell = row*8 + (kg^(row&7)).
template<int MODE>  // 0: fp32 out, 1: bf16 out
__global__ __launch_bounds__(256, 4) void bgemm(
    const u16* __restrict__ A, const u16* __restrict__ Bw,
    void* __restrict__ Cout, int K)
{
  __shared__ u16 ldsA[128 * 64];
  __shared__ u16 ldsB[128 * 64];
  const int orig = blockIdx.x;
  const int swz  = (orig & 7) * 256 + (orig >> 3);   // bijective: 2048 % 8 == 0
  const int m0 = (swz >> 3) * 128;
  const int n0 = (swz & 7) * 128;
  const int t  = threadIdx.x;
  const int l  = t & 63;
  const int wid = t >> 6;
  const int wr = wid >> 1, wc = wid & 1;
  const int lr = l & 15, lk = l >> 4;

  f32x4 acc[4][4];
#pragma unroll
  for (int i = 0; i < 4; ++i)
#pragma unroll
    for (int j = 0; j < 4; ++j) acc[i][j] = (f32x4){0.f, 0.f, 0.f, 0.f};

  int srow[4], sck[4];
#pragma unroll
  for (int j = 0; j < 4; ++j) {
    int flat = j * 256 + t;
    srow[j] = flat >> 3;
    sck[j]  = (flat & 7) ^ (srow[j] & 7);
  }

  const int nkt = K >> 6;
  for (int kt = 0; kt < nkt; ++kt) {
#pragma unroll
    for (int j = 0; j < 4; ++j)
      GLOAD16(A + (size_t)(m0 + srow[j]) * K + kt * 64 + sck[j] * 8, &ldsA[(j * 256 + t) * 8]);
#pragma unroll
    for (int j = 0; j < 4; ++j)
      GLOAD16(Bw + (size_t)(n0 + srow[j]) * K + kt * 64 + sck[j] * 8, &ldsB[(j * 256 + t) * 8]);
    __syncthreads();   // compiler drains vmcnt before barrier
#pragma unroll
    for (int ks = 0; ks < 2; ++ks) {
      bf16x8 af[4], bfr[4];
      const int kg = ks * 4 + lk;
#pragma unroll
      for (int mf = 0; mf < 4; ++mf) {
        int row  = wr * 64 + mf * 16 + lr;
        int cell = row * 8 + (kg ^ (row & 7));
        af[mf] = *reinterpret_cast<const bf16x8*>(&ldsA[cell * 8]);
      }
#pragma unroll
      for (int nf = 0; nf < 4; ++nf) {
        int row  = wc * 64 + nf * 16 + lr;
        int cell = row * 8 + (kg ^ (row & 7));
        bfr[nf] = *reinterpret_cast<const bf16x8*>(&ldsB[cell * 8]);
      }
#pragma unroll
      for (int mf = 0; mf < 4; ++mf)
#pragma unroll
        for (int nf = 0; nf < 4; ++nf)
          acc[mf][nf] = __builtin_amdgcn_mfma_f32_16x16x32_bf16(af[mf], bfr[nf], acc[mf][nf], 0, 0, 0);
    }
    __syncthreads();
  }
#pragma unroll
  for (int mf = 0; mf < 4; ++mf) {
#pragma unroll
    for (int nf = 0; nf < 4; ++nf) {
      int n = n0 + wc * 64 + nf * 16 + lr;
      int mbase = m0 + wr * 64 + mf * 16 + lk * 4;
#pragma unroll
      for (int r = 0; r < 4; ++r) {
        if (MODE == 0) ((float*)Cout)[(size_t)(mbase + r) * 1024 + n] = acc[mf][nf][r];
        else           ((u16*)Cout)[(size_t)(mbase + r) * 1024 + n] = f2bf(acc[mf][nf][r]);
      }
    }
  }
}

// ===================== fp32 -> bf16 convert (weights) =====================
__global__ __launch_bounds__(256) void cvt32to16(const float* __restrict__ in, u16* __restrict__ out)
{
  size_t i = ((size_t)blockIdx.x * 256 + threadIdx.x) * 8;
  f32x4 a = *reinterpret_cast<const f32x4*>(&in[i]);
  f32x4 b = *reinterpret_cast<const f32x4*>(&in[i + 4]);
  u16x8 o;
#pragma unroll
  for (int j = 0; j < 4; ++j) { o[j] = f2bf(a[j]); o[4 + j] = f2bf(b[j]); }
  *reinterpret_cast<u16x8*>(&out[i]) = o;
}

// ===================== residual (lo) of bf16 rounding for the 16 w rows =====================
__global__ __launch_bounds__(256) void cvtlo(const float* __restrict__ ipw, u16* __restrict__ wlo)
{
  size_t e = ((size_t)blockIdx.x * 256 + threadIdx.x) * 8;   // 16384 elems total
  f32x4 a = *reinterpret_cast<const f32x4*>(&ipw[1048576 + e]);
  f32x4 b = *reinterpret_cast<const f32x4*>(&ipw[1048576 + e + 4]);
  u16x8 o;
#pragma unroll
  for (int j = 0; j < 4; ++j) {
    u16 h = f2bf(a[j]); o[j]     = f2bf(a[j] - bf2f(h));
    u16 g = f2bf(b[j]); o[4 + j] = f2bf(b[j] - bf2f(g));
  }
  *reinterpret_cast<u16x8*>(&wlo[e]) = o;
}

// ===================== wsplit: x->bf16 (hi) + compensated-MFMA w projection =====================
__global__ __launch_bounds__(256) void wsplit(
    const float* __restrict__ x, const u16* __restrict__ wbf, const u16* __restrict__ wlo,
    u16* __restrict__ xbf, float* __restrict__ wbufT)
{
  __shared__ u16 hi[64 * 64];   // 8 KB
  __shared__ u16 lo[64 * 64];   // 8 KB
  const int r0 = blockIdx.x * 64;
  const int t  = threadIdx.x;
  const int w  = t >> 6, l = t & 63;
  const int lr = l & 15, lk = l >> 4;
  const int c8   = t & 7;       // staging col-chunk (8 floats)
  const int srow = t >> 3;      // staging row 0..31 (+32 on pass 2)

  f32x4 acc = (f32x4){0.f, 0.f, 0.f, 0.f};

  for (int kt = 0; kt < 16; ++kt) {
    __syncthreads();            // previous iter's LDS reads done
#pragma unroll
    for (int p = 0; p < 2; ++p) {
      int row = srow + 32 * p;
      const float* gp = &x[(size_t)(r0 + row) * 1024 + kt * 64 + c8 * 8];
      f32x4 a = *reinterpret_cast<const f32x4*>(gp);
      f32x4 b = *reinterpret_cast<const f32x4*>(gp + 4);
      u16x8 h8, l8;
#pragma unroll
      for (int j = 0; j < 4; ++j) {
        u16 ha = f2bf(a[j]); h8[j]     = ha; l8[j]     = f2bf(a[j] - bf2f(ha));
        u16 hb = f2bf(b[j]); h8[4 + j] = hb; l8[4 + j] = f2bf(b[j] - bf2f(hb));
      }
      int cell = row * 8 + (c8 ^ (row & 7));
      *reinterpret_cast<u16x8*>(&hi[cell * 8]) = h8;
      *reinterpret_cast<u16x8*>(&lo[cell * 8]) = l8;
      *reinterpret_cast<u16x8*>(&xbf[(size_t)(r0 + row) * 1024 + kt * 64 + c8 * 8]) = h8;
    }
    __syncthreads();
    // MFMA: wave w owns x rows w*16..w*16+15; C cols = 16 heads.
#pragma unroll
    for (int ks = 0; ks < 2; ++ks) {
      int row  = w * 16 + lr;
      int cell = row * 8 + ((ks * 4 + lk) ^ (row & 7));
      bf16x8 ah = *reinterpret_cast<const bf16x8*>(&hi[cell * 8]);
      bf16x8 al = *reinterpret_cast<const bf16x8*>(&lo[cell * 8]);
      bf16x8 bh = *reinterpret_cast<const bf16x8*>(&wbf[(size_t)(1024 + lr) * 1024 + kt * 64 + ks * 32 + lk * 8]);
      bf16x8 bl = *reinterpret_cast<const bf16x8*>(&wlo[(size_t)lr * 1024 + kt * 64 + ks * 32 + lk * 8]);
      acc = __builtin_amdgcn_mfma_f32_16x16x32_bf16(ah, bh, acc, 0, 0, 0);
      acc = __builtin_amdgcn_mfma_f32_16x16x32_bf16(al, bh, acc, 0, 0, 0);
      acc = __builtin_amdgcn_mfma_f32_16x16x32_bf16(ah, bl, acc, 0, 0, 0);
    }
  }
  // C mapping: col=lane&15 (=h), row=(lane>>4)*4+reg
#pragma unroll
  for (int r = 0; r < 4; ++r)
    wbufT[(size_t)lr * M_ + r0 + w * 16 + lk * 4 + r] = acc[r];
}

// ===================== fused per-(b,h,c): conv + cumsum + L(MFMA) + Y_diag + norm + states =====================
__global__ __launch_bounds__(256) void chunk_kernel(
    const u16* __restrict__ xi,        // [M][1024] bf16 (in_proj out, pre-conv)
    const float* __restrict__ cw, const float* __restrict__ cb,
    const float* __restrict__ wbufT, const float* __restrict__ w_base,
    u16* __restrict__ ybuf, float* __restrict__ Acum, float* __restrict__ acbuf,
    float* __restrict__ normd, float* __restrict__ states, float* __restrict__ ndbuf)
{
  int bi = blockIdx.x;               // b*1024 + h*64 + c
  int c  = bi & 63;
  int h  = (bi >> 6) & 15;
  int b  = bi >> 10;
  int bh = b * 16 + h;
  int t  = threadIdx.x;
  __shared__ u16 xis[67][64];        // raw xi tile (halo 3), bf16
  __shared__ u16 xsT[64][66];        // conv output, transposed [n][s], bf16
  __shared__ float pc[CH], m1s[CH], dsv[CH];
  __shared__ float wls[4][64];       // conv weights transposed [tap][ch]
  __shared__ float cbs[64];
  size_t m0 = (size_t)b * S_ + (size_t)c * CH;
  size_t abase = ((size_t)bh * NC + c) * CH;

  wls[t & 3][t >> 2] = cw[(size_t)h * 256 + t];
  if (t < 64) cbs[t] = cb[h * 64 + t];

  {
    int g8  = t & 7;
    int hr0 = t >> 3;
    for (int hr = hr0; hr < 67; hr += 32) {
      u16x8 v = {0, 0, 0, 0, 0, 0, 0, 0};
      if (!(c == 0 && hr < 3))
        v = *reinterpret_cast<const u16x8*>(&xi[(m0 - 3 + hr) * DM + h * 64 + g8 * 8]);
      *reinterpret_cast<u16x8*>(&xis[hr][g8 * 8]) = v;
    }
  }

  if (t < 64) {
    float p = wbufT[(size_t)h * M_ + m0 + t] * w_base[h];
#pragma unroll
    for (int off = 1; off < 64; off <<= 1) {
      float v = __shfl_up(p, off);
      if (t >= off) p += v;
    }
    Acum[abase + t] = p;
    if (t == 63) acbuf[(size_t)bh * NC + c] = p;
    pc[t] = p;
    float rmin = p;
#pragma unroll
    for (int off = 1; off < 64; off <<= 1) {
      float v = __shfl_up(rmin, off);
      if (t >= off) rmin = fminf(rmin, v);
    }
    m1s[t] = p - rmin;
    float minall = __shfl(rmin, 63);
    dsv[t] = __expf(minall - p);
  }
  __syncthreads();

  // conv: thread owns channel n, 16 consecutive rows; sliding 4-tap window
  {
    int n  = t & 63;
    int lb = (t >> 6) * 16;
    float w0 = wls[0][n], w1 = wls[1][n], w2 = wls[2][n], w3 = wls[3][n];
    float bias = cbs[n];
    float a = bf2f(xis[lb + 0][n]);
    float bv = bf2f(xis[lb + 1][n]);
    float cv = bf2f(xis[lb + 2][n]);
    u16x8 o0, o1;
#pragma unroll
    for (int r = 0; r < 16; ++r) {
      float dv = bf2f(xis[lb + r + 3][n]);
      float s = fmaf(w3, dv, fmaf(w2, cv, fmaf(w1, bv, fmaf(w0, a, bias))));
      if (r < 8) o0[r] = f2bf(s); else o1[r - 8] = f2bf(s);
      a = bv; bv = cv; cv = dv;
    }
    *reinterpret_cast<u16x8*>(&xsT[n][lb]) = o0;
    *reinterpret_cast<u16x8*>(&xsT[n][lb + 8]) = o1;
  }
  __syncthreads();

  // MFMA phase: wave w owns output rows w*16..w*16+15.
  {
    int w = t >> 6, l = t & 63;
    int lr = l & 15, lk = l >> 4;
    int row = w * 16 + lr;
    float pr = pc[row], m1r = m1s[row];
    bf16x8 afr[2];
    float np = 0.f;
#pragma unroll
    for (int ks = 0; ks < 2; ++ks) {
      int sbase = ks * 32 + lk * 8;
      u16x8 av;
#pragma unroll
      for (int j = 0; j < 8; ++j) {
        int s = sbase + j;
        float L = (s <= row) ? __expf(pr - pc[s] - m1r) : 0.f;
        np += L;
        av[j] = f2bf(L);
      }
      afr[ks] = __builtin_bit_cast(bf16x8, av);
    }
    np += __shfl_xor(np, 16);
    np += __shfl_xor(np, 32);
    if (lk == 0) normd[abase + row] = np;

    f32x4 acc[4];
#pragma unroll
    for (int nf = 0; nf < 4; ++nf) acc[nf] = (f32x4){0.f, 0.f, 0.f, 0.f};
#pragma unroll
    for (int ks = 0; ks < 2; ++ks)
#pragma unroll
      for (int nf = 0; nf < 4; ++nf) {
        bf16x8 bfr = *reinterpret_cast<const bf16x8*>(&xsT[nf * 16 + lr][ks * 32 + lk * 8]);
        acc[nf] = __builtin_amdgcn_mfma_f32_16x16x32_bf16(afr[ks], bfr, acc[nf], 0, 0, 0);
      }
#pragma unroll
    for (int nf = 0; nf < 4; ++nf)
#pragma unroll
      for (int r = 0; r < 4; ++r)
        ybuf[(m0 + w * 16 + lk * 4 + r) * DM + h * 64 + nf * 16 + lr] = f2bf(acc[nf][r]);
  }

  if (t < 64) {
    float acc = 0.f;
#pragma unroll
    for (int l8 = 0; l8 < 64; l8 += 8) {
      u16x8 xv = *reinterpret_cast<const u16x8*>(&xsT[t][l8]);
#pragma unroll
      for (int j = 0; j < 8; ++j) acc = fmaf(dsv[l8 + j], bf2f(xv[j]), acc);
    }
    states[((size_t)bh * NC + c) * DN + t] = acc;
    float v = dsv[t];
#pragma unroll
    for (int off = 32; off >= 1; off >>= 1) v += __shfl_down(v, off);
    if (t == 0) ndbuf[(size_t)bh * NC + c] = v;
  }
}

// ===================== inter-chunk propagation =====================
__global__ __launch_bounds__(256) void interchunk_kernel(
    const float* __restrict__ acbuf, const float* __restrict__ states,
    const float* __restrict__ ndbuf, float* __restrict__ nstates, float* __restrict__ nndbuf)
{
  int bh = blockIdx.x;
  int t  = threadIdx.x;
  __shared__ float Ssum[NC], minP[NC], ndl[NC];
  if (t < 64) {
    float ac = acbuf[(size_t)bh * NC + t];
    float S = ac;
#pragma unroll
    for (int off = 1; off < 64; off <<= 1) {
      float v = __shfl_up(S, off);
      if (t >= off) S += v;
    }
    float Pc = S - ac;
    float mp = Pc;
#pragma unroll
    for (int off = 1; off < 64; off <<= 1) {
      float v = __shfl_up(mp, off);
      if (t >= off) mp = fminf(mp, v);
    }
    Ssum[t] = S;
    minP[t] = mp;
    ndl[t]  = ndbuf[(size_t)bh * NC + t];
  }
  __syncthreads();
  int n  = t & 63;
  int r0 = t >> 6;
  for (int r = 0; r < 16; ++r) {
    int z = r0 + r * 4;
    float mpz = minP[z];
    float acc = 0.f;
    for (int j = 0; j < z; ++j) {
      float e = __expf(mpz - Ssum[j]);
      acc = fmaf(e, states[((size_t)bh * NC + j) * DN + n], acc);
    }
    nstates[((size_t)bh * NC + z) * DN + n] = acc;
  }
  if (t < 64) {
    int z = t;
    float mpz = minP[z];
    float acc = 0.f;
    for (int j = 0; j < z; ++j) acc = fmaf(__expf(mpz - Ssum[j]), ndl[j], acc);
    nndbuf[(size_t)bh * NC + z] = acc;
  }
}

// ===================== final: y = (Y_diag + states_off*sdo) / (norm_diag + nd_off*sdo) =====================
__global__ __launch_bounds__(256) void final_kernel(
    const float* __restrict__ Acum, const float* __restrict__ normd,
    const float* __restrict__ nstates, const float* __restrict__ nndbuf,
    u16* __restrict__ ybuf)
{
  int bi = blockIdx.x;
  int c  = bi & 63;
  int h  = (bi >> 6) & 15;
  int b  = bi >> 10;
  int bh = b * 16 + h;
  int t  = threadIdx.x;
  __shared__ float sdo[CH], nrm[CH], sto[DN];
  __shared__ float ndo_s;
  size_t abase = ((size_t)bh * NC + c) * CH;
  if (t < 64) {
    float p = Acum[abase + t];
    float m3 = p;
#pragma unroll
    for (int off = 32; off >= 1; off >>= 1) m3 = fmaxf(m3, __shfl_down(m3, off));
    m3 = __shfl(m3, 0);
    sdo[t] = __expf(p - m3);
    nrm[t] = normd[abase + t];
    sto[t] = nstates[((size_t)bh * NC + c) * DN + t];
    if (t == 0) ndo_s = nndbuf[(size_t)bh * NC + c];
  }
  __syncthreads();
  size_t m0 = (size_t)b * S_ + (size_t)c * CH;
  int g  = t & 7;
  int l0 = t >> 3;
  float ndo = ndo_s;
  for (int li = l0; li < 64; li += 32) {
    size_t a = (m0 + li) * DM + h * DN + g * 8;
    u16x8 v = *reinterpret_cast<u16x8*>(&ybuf[a]);
    float sd = sdo[li];
    float rec = 1.f / (nrm[li] + ndo * sd);
    u16x8 o;
#pragma unroll
    for (int jj = 0; jj < 8; ++jj) {
      float yd = bf2f(v[jj]);
      o[jj] = f2bf((yd + sto[g * 8 + jj] * sd) * rec);
    }
    *reinterpret_cast<u16x8*>(&ybuf[a]) = o;
  }
}

// ===================== launch =====================
extern "C" void kernel_launch(void* const* d_in, const int* in_sizes, int n_in,
                              void* d_out, int out_size, void* d_ws, size_t ws_size,
                              hipStream_t stream) {
  const float* x          = (const float*)d_in[0];
  const float* in_proj_w  = (const float*)d_in[1];
  const float* conv_w     = (const float*)d_in[2];
  const float* conv_b     = (const float*)d_in[3];
  const float* w_base     = (const float*)d_in[4];
  const float* out_proj_w = (const float*)d_in[5];
  float* out = (float*)d_out;
  char* ws = (char*)d_ws;

  // workspace layout (~149 MB)
  u16*   wbf_in  = (u16*)  (ws + 0);          // [1040][1024] bf16 (all in_proj rows)
  u16*   wbf_out = (u16*)  (ws + 2129920);
  u16*   wlo16   = (u16*)  (ws + 4227072);    // [16][1024] bf16 residuals
  float* wbufT   = (float*)(ws + 4259840);
  float* Acum    = (float*)(ws + 6356992);
  float* acbuf   = (float*)(ws + 8454144);
  float* normd   = (float*)(ws + 8486912);
  float* states  = (float*)(ws + 10584064);
  float* ndbuf   = (float*)(ws + 12681216);
  float* nstates = (float*)(ws + 12713984);
  float* nndbuf  = (float*)(ws + 14811136);
  u16*   xbf     = (u16*)  (ws + 14843904);   // [M][1024] bf16 of x; reused as ybuf
  u16*   xibf    = (u16*)  (ws + 81952768);   // [M][1024] bf16 xi (in_proj out)
  u16*   ybuf    = xbf;

  cvt32to16<<<520, 256, 0, stream>>>(in_proj_w, wbf_in);     // 1040 rows incl. w rows
  cvt32to16<<<512, 256, 0, stream>>>(out_proj_w, wbf_out);
  cvtlo<<<8, 256, 0, stream>>>(in_proj_w, wlo16);
  wsplit<<<512, 256, 0, stream>>>(x, wbf_in, wlo16, xbf, wbufT);
  bgemm<1><<<2048, 256, 0, stream>>>(xbf, wbf_in, (void*)xibf, DM);
  chunk_kernel<<<8192, 256, 0, stream>>>(xibf, conv_w, conv_b, wbufT, w_base,
                                         ybuf, Acum, acbuf, normd, states, ndbuf);
  interchunk_kernel<<<128, 256, 0, stream>>>(acbuf, states, ndbuf, nstates, nndbuf);
  final_kernel<<<8192, 256, 0, stream>>>(Acum, normd, nstates, nndbuf, ybuf);
  bgemm<0><<<2048, 256, 0, stream>>>(ybuf, wbf_out, (void*)out, DM);
}